// Round 8
// baseline (117.155 us; speedup 1.0000x reference)
//
#include <hip/hip_runtime.h>
#include <math.h>

#define IN_DIM 512
#define OUT_DIM 128
#define BM 64
#define NKT (IN_DIM / 64)  // 8

typedef __attribute__((ext_vector_type(8))) __bf16 bf16x8;
typedef __attribute__((ext_vector_type(2))) __bf16 bf16x2;
typedef __attribute__((ext_vector_type(4))) float f32x4;
typedef __attribute__((ext_vector_type(2))) float f32x2;

// Manual RNE fp32->bf16 (bit ops) — round-5-proven codegen; used in epilogue
// and wt2 prep.
__device__ inline unsigned short f2bf(float f) {
    unsigned u = __float_as_uint(f);
    u += 0x7FFFu + ((u >> 16) & 1u);  // round-to-nearest-even
    return (unsigned short)(u >> 16);
}

// In-register fp32x8 -> bf16x8 via native paired casts (v_cvt_pk_bf16_f32).
// Inputs are consumed immediately (short live ranges — round-6 lesson).
__device__ inline bf16x8 cvt8(const float4& lo, const float4& hi) {
    bf16x2 p0 = {(__bf16)lo.x, (__bf16)lo.y};
    bf16x2 p1 = {(__bf16)lo.z, (__bf16)lo.w};
    bf16x2 p2 = {(__bf16)hi.x, (__bf16)hi.y};
    bf16x2 p3 = {(__bf16)hi.z, (__bf16)hi.w};
    uint4 u = {__builtin_bit_cast(unsigned, p0), __builtin_bit_cast(unsigned, p1),
               __builtin_bit_cast(unsigned, p2), __builtin_bit_cast(unsigned, p3)};
    return __builtin_bit_cast(bf16x8, u);
}

// w [512][128] f32 -> wt2 k-interleaved bf16: wt2[(k>>3)*128 + n][k&7]
__global__ void wt2_kernel(const float* __restrict__ w, unsigned short* __restrict__ wt2) {
    int idx = blockIdx.x * 256 + threadIdx.x;  // 65536 total
    int k = idx >> 7;
    int n = idx & 127;
    wt2[(((k >> 3) * 128) + n) * 8 + (k & 7)] = f2bf(w[idx]);
}

// ---------------------------------------------------------------------------
// z_bf[M,128](bf16) = x[M,512] @ w[512,128] via bf16 MFMA, fp32 accumulate.
// NO LDS, NO barriers: each lane loads its MFMA A-fragment directly from
// global (8 consecutive fp32 = 32 B; a wave's fragment loads cover 16 rows
// x full 128 B lines per (kt,ks)), converts in-register, and reads B
// fragments from the L2-resident k-interleaved wt2. Fully unrolled ->
// compiler pipelines next-step loads under current MFMAs with no barrier
// drain. 4 waves (2x2), wave = 32x64 out; wn=0/1 waves' duplicate A reads
// hit L1.
// ---------------------------------------------------------------------------
__global__ __launch_bounds__(256, 4) void gemm_mfma(const float* __restrict__ x,
                                                    const unsigned short* __restrict__ wt2,
                                                    unsigned short* __restrict__ zb,
                                                    int M) {
    const int tid  = threadIdx.x;
    const int lane = tid & 63;
    const int wid  = tid >> 6;
    const int wm   = wid >> 1;  // 0..1
    const int wn   = wid & 1;   // 0..1
    const int block_row = blockIdx.x * BM;

    const int fr  = lane & 15;  // fragment row (A) / col (B)
    const int fk4 = lane >> 4;  // k-octet group 0..3

    f32x4 acc[2][4];
#pragma unroll
    for (int i = 0; i < 2; ++i)
#pragma unroll
        for (int j = 0; j < 4; ++j) acc[i][j] = (f32x4){0.f, 0.f, 0.f, 0.f};

    // Per-lane A base pointers for the two mf fragments (rows clamped; garbage
    // rows are computed but never stored).
    const float* xa[2];
#pragma unroll
    for (int mf = 0; mf < 2; ++mf) {
        int r = block_row + wm * 32 + mf * 16 + fr;
        r = (r < M) ? r : (M - 1);
        xa[mf] = x + (size_t)r * IN_DIM + fk4 * 8;
    }
    // Per-lane B base pointer in wt2 (element units)
    const unsigned short* wtb = wt2 + (size_t)fk4 * 1024 + (wn * 64 + fr) * 8;

#pragma unroll
    for (int kt = 0; kt < NKT; ++kt) {
#pragma unroll
        for (int ks = 0; ks < 2; ++ks) {
            const int ko = kt * 64 + ks * 32;
            // A fragments: direct global load + in-register convert
            bf16x8 af[2];
#pragma unroll
            for (int mf = 0; mf < 2; ++mf) {
                const float4 lo = *(const float4*)(xa[mf] + ko);
                const float4 hi = *(const float4*)(xa[mf] + ko + 4);
                af[mf] = cvt8(lo, hi);
            }
            // B fragments: L2-resident wt2
            bf16x8 bv[4];
#pragma unroll
            for (int nf = 0; nf < 4; ++nf)
                bv[nf] = *(const bf16x8*)(wtb + kt * 8192 + ks * 4096 + nf * 128);
#pragma unroll
            for (int mf = 0; mf < 2; ++mf)
#pragma unroll
                for (int nf = 0; nf < 4; ++nf)
                    acc[mf][nf] = __builtin_amdgcn_mfma_f32_16x16x32_bf16(
                        af[mf], bv[nf], acc[mf][nf], 0, 0, 0);
        }
    }

    // C/D layout: col = lane&15, row = (lane>>4)*4 + reg. Store bf16 (bit-op
    // f2bf — round-5-proven epilogue codegen).
    const int crow0 = (lane >> 4) * 4;
    const int ccol  = lane & 15;
#pragma unroll
    for (int mf = 0; mf < 2; ++mf)
#pragma unroll
        for (int r = 0; r < 4; ++r) {
            const int grow = block_row + wm * 32 + mf * 16 + crow0 + r;
            if (grow < M) {
                unsigned short* zr = zb + (size_t)grow * OUT_DIM + wn * 64 + ccol;
#pragma unroll
                for (int nf = 0; nf < 4; ++nf)
                    zr[nf * 16] = f2bf(acc[mf][nf][r]);
            }
        }
}

// ---------------------------------------------------------------------------
// Decode: out[e] = sigmoid( sum_k z[a_e,k]*z[b_e,k]*w3[k] ), z in bf16.
// 16 lanes per edge, 4 edges/wave, grid-stride UNROLLED x2 (2x MLP).
// ---------------------------------------------------------------------------
__device__ inline float dotw3(const uint4& ua, const uint4& ub, const f32x2* w3v) {
    const unsigned pa[4] = {ua.x, ua.y, ua.z, ua.w};
    const unsigned pb[4] = {ub.x, ub.y, ub.z, ub.w};
    f32x2 vv = (f32x2){0.f, 0.f};
#pragma unroll
    for (int i = 0; i < 4; ++i) {
        f32x2 A = (f32x2){__uint_as_float(pa[i] << 16),
                          __uint_as_float(pa[i] & 0xFFFF0000u)};
        f32x2 B = (f32x2){__uint_as_float(pb[i] << 16),
                          __uint_as_float(pb[i] & 0xFFFF0000u)};
        vv += (A * B) * w3v[i];  // v_pk_mul_f32 + v_pk_fma_f32
    }
    return vv.x + vv.y;
}

__global__ __launch_bounds__(256) void decode_kernel(const unsigned short* __restrict__ zb,
                                                     const int* __restrict__ e1,
                                                     const int* __restrict__ e2,
                                                     const float* __restrict__ w3,
                                                     float* __restrict__ out,
                                                     int E1, int E2) {
    const int tid  = threadIdx.x;
    const int lane = tid & 63;
    const int sub  = lane & 15;   // lane within 16-group
    const int sg   = lane >> 4;   // edge slot within wave (0..3)
    const int Etot = E1 + E2;
    const int nq   = (Etot + 3) >> 2;

    f32x2 w3v[4];
    {
        const float4 wlo = *(const float4*)(w3 + sub * 8);
        const float4 whi = *(const float4*)(w3 + sub * 8 + 4);
        w3v[0] = (f32x2){wlo.x, wlo.y};
        w3v[1] = (f32x2){wlo.z, wlo.w};
        w3v[2] = (f32x2){whi.x, whi.y};
        w3v[3] = (f32x2){whi.z, whi.w};
    }

    const int wave = blockIdx.x * 4 + (tid >> 6);
    const int S    = gridDim.x * 4;  // stride in quads

    for (int q = wave; q < nq; q += 2 * S) {
        const int q2    = q + S;
        const bool has2 = (q2 < nq);

        const int e_a = q * 4 + sg;
        const int e_b = has2 ? (q2 * 4 + sg) : e_a;
        const int ca  = min(e_a, Etot - 1);
        const int cb  = min(e_b, Etot - 1);

        // both index loads up front
        const int2 ia = (ca < E1) ? ((const int2*)e1)[ca] : ((const int2*)e2)[ca - E1];
        const int2 ib = (cb < E1) ? ((const int2*)e1)[cb] : ((const int2*)e2)[cb - E1];

        // all 4 row gathers issued before any math
        const uint4 a1 = *(const uint4*)(zb + (size_t)ia.x * OUT_DIM + sub * 8);
        const uint4 b1 = *(const uint4*)(zb + (size_t)ia.y * OUT_DIM + sub * 8);
        const uint4 a2 = *(const uint4*)(zb + (size_t)ib.x * OUT_DIM + sub * 8);
        const uint4 b2 = *(const uint4*)(zb + (size_t)ib.y * OUT_DIM + sub * 8);

        float v1 = dotw3(a1, b1, w3v);
        float v2 = dotw3(a2, b2, w3v);

        v1 += __shfl_xor(v1, 8);  v2 += __shfl_xor(v2, 8);
        v1 += __shfl_xor(v1, 4);  v2 += __shfl_xor(v2, 4);
        v1 += __shfl_xor(v1, 2);  v2 += __shfl_xor(v2, 2);
        v1 += __shfl_xor(v1, 1);  v2 += __shfl_xor(v2, 1);

        if (sub == 0) {
            if (e_a < Etot) out[e_a] = 1.f / (1.f + __expf(-v1));
            if (has2 && e_b < Etot) out[e_b] = 1.f / (1.f + __expf(-v2));
        }
    }
}

extern "C" void kernel_launch(void* const* d_in, const int* in_sizes, int n_in,
                              void* d_out, int out_size, void* d_ws, size_t ws_size,
                              hipStream_t stream) {
    const float* x  = (const float*)d_in[0];
    const int*   e1 = (const int*)d_in[1];
    const int*   e2 = (const int*)d_in[2];
    const float* w  = (const float*)d_in[3];
    const float* w3 = (const float*)d_in[4];

    float* out = (float*)d_out;

    const int M  = in_sizes[0] / IN_DIM;  // 100000
    const int E1 = in_sizes[1] / 2;       // 300000
    const int E2 = in_sizes[2] / 2;       // 300000

    // workspace: z_bf [M,128] bf16 (25.6 MB), then wt2 [512x128] bf16 (128 KB)
    unsigned short* zbuf = (unsigned short*)d_ws;
    unsigned short* wt2  = zbuf + (size_t)M * OUT_DIM;

    wt2_kernel<<<(IN_DIM * OUT_DIM) / 256, 256, 0, stream>>>(w, wt2);
    gemm_mfma<<<(M + BM - 1) / BM, 256, 0, stream>>>(x, wt2, zbuf, M);
    decode_kernel<<<2048, 256, 0, stream>>>(zbuf, e1, e2, w3, out, E1, E2);
}

// Round 9
// 115.560 us; speedup vs baseline: 1.0138x; 1.0138x over previous
//
#include <hip/hip_runtime.h>
#include <math.h>

#define IN_DIM 512
#define OUT_DIM 128
#define BM 64

typedef __attribute__((ext_vector_type(8))) __bf16 bf16x8;
typedef __attribute__((ext_vector_type(2))) __bf16 bf16x2;
typedef __attribute__((ext_vector_type(4))) float f32x4;
typedef __attribute__((ext_vector_type(2))) float f32x2;

// Manual RNE fp32->bf16 (bit ops) — r5-proven codegen for epilogue/prep.
__device__ inline unsigned short f2bf(float f) {
    unsigned u = __float_as_uint(f);
    u += 0x7FFFu + ((u >> 16) & 1u);  // round-to-nearest-even
    return (unsigned short)(u >> 16);
}

// In-register fp32x8 -> bf16x8 via native paired casts (v_cvt_pk_bf16_f32),
// consumed immediately (short live ranges).
__device__ inline bf16x8 cvt8(const float4& lo, const float4& hi) {
    bf16x2 p0 = {(__bf16)lo.x, (__bf16)lo.y};
    bf16x2 p1 = {(__bf16)lo.z, (__bf16)lo.w};
    bf16x2 p2 = {(__bf16)hi.x, (__bf16)hi.y};
    bf16x2 p3 = {(__bf16)hi.z, (__bf16)hi.w};
    uint4 u = {__builtin_bit_cast(unsigned, p0), __builtin_bit_cast(unsigned, p1),
               __builtin_bit_cast(unsigned, p2), __builtin_bit_cast(unsigned, p3)};
    return __builtin_bit_cast(bf16x8, u);
}

// w [512][128] f32 -> wt2 k-interleaved bf16: wt2[(k>>3)*128 + n][k&7]
__global__ void wt2_kernel(const float* __restrict__ w, unsigned short* __restrict__ wt2) {
    int idx = blockIdx.x * 256 + threadIdx.x;  // 65536 total
    int k = idx >> 7;
    int n = idx & 127;
    wt2[(((k >> 3) * 128) + n) * 8 + (k & 7)] = f2bf(w[idx]);
}

// ---------------------------------------------------------------------------
// z_bf[M,128](bf16) = x[M,512] @ w[512,128] via bf16 MFMA, fp32 accumulate.
// No LDS, no barriers. EXPLICIT 2-deep register ping-pong pipeline: named
// buffers (A in fp32: 16 VGPR/buf; B in bf16x8: 16 VGPR/buf); loads for
// step s+1 and s+2 are issued before step s's MFMAs, so ~8-16 global loads
// stay in flight per wave at all times (structural counted-vmcnt). Rule #20:
// all buffers are named scalars, no runtime-indexed arrays.
// 4 waves (2x2), wave = 32x64 out. 16 k-steps of 32.
// ---------------------------------------------------------------------------
__global__ __launch_bounds__(256, 4) void gemm_mfma(const float* __restrict__ x,
                                                    const unsigned short* __restrict__ wt2,
                                                    unsigned short* __restrict__ zb,
                                                    int M) {
    const int tid  = threadIdx.x;
    const int lane = tid & 63;
    const int wid  = tid >> 6;
    const int wm   = wid >> 1;  // 0..1
    const int wn   = wid & 1;   // 0..1
    const int block_row = blockIdx.x * BM;

    const int fr  = lane & 15;  // fragment row (A) / col (B)
    const int fk4 = lane >> 4;  // k-octet group 0..3

    f32x4 acc[2][4];
#pragma unroll
    for (int i = 0; i < 2; ++i)
#pragma unroll
        for (int j = 0; j < 4; ++j) acc[i][j] = (f32x4){0.f, 0.f, 0.f, 0.f};

    // Per-lane A base pointers (rows clamped; clamped rows never stored).
    int r0 = block_row + wm * 32 + fr;       r0 = (r0 < M) ? r0 : (M - 1);
    int r1 = block_row + wm * 32 + 16 + fr;  r1 = (r1 < M) ? r1 : (M - 1);
    const float* pa0 = x + (size_t)r0 * IN_DIM + fk4 * 8;
    const float* pa1 = x + (size_t)r1 * IN_DIM + fk4 * 8;
    // Per-lane B pointer in wt2 (element units); step stride 4096 elems.
    const unsigned short* pb = wt2 + (size_t)fk4 * 1024 + (wn * 64 + fr) * 8;

    // ---- ping-pong buffers (named, rule #20) ----
    float4 A0l0, A0h0, A0l1, A0h1;  // buf0: A fp32, mf=0/1, lo/hi
    float4 A1l0, A1h0, A1l1, A1h1;  // buf1
    bf16x8 B00, B01, B02, B03;      // buf0: B nf=0..3
    bf16x8 B10, B11, B12, B13;      // buf1

    // prologue: load step 0 into buf0
    A0l0 = *(const float4*)(pa0 + 0);  A0h0 = *(const float4*)(pa0 + 4);
    A0l1 = *(const float4*)(pa1 + 0);  A0h1 = *(const float4*)(pa1 + 4);
    B00 = *(const bf16x8*)(pb + 0);    B01 = *(const bf16x8*)(pb + 128);
    B02 = *(const bf16x8*)(pb + 256);  B03 = *(const bf16x8*)(pb + 384);

    for (int p = 0; p < 8; ++p) {
        // issue loads for step 2p+1 into buf1 (before any compute)
        A1l0 = *(const float4*)(pa0 + 32);  A1h0 = *(const float4*)(pa0 + 36);
        A1l1 = *(const float4*)(pa1 + 32);  A1h1 = *(const float4*)(pa1 + 36);
        B10 = *(const bf16x8*)(pb + 4096); B11 = *(const bf16x8*)(pb + 4224);
        B12 = *(const bf16x8*)(pb + 4352); B13 = *(const bf16x8*)(pb + 4480);

        // compute step 2p from buf0
        {
            bf16x8 af0 = cvt8(A0l0, A0h0);
            bf16x8 af1 = cvt8(A0l1, A0h1);
            acc[0][0] = __builtin_amdgcn_mfma_f32_16x16x32_bf16(af0, B00, acc[0][0], 0, 0, 0);
            acc[0][1] = __builtin_amdgcn_mfma_f32_16x16x32_bf16(af0, B01, acc[0][1], 0, 0, 0);
            acc[0][2] = __builtin_amdgcn_mfma_f32_16x16x32_bf16(af0, B02, acc[0][2], 0, 0, 0);
            acc[0][3] = __builtin_amdgcn_mfma_f32_16x16x32_bf16(af0, B03, acc[0][3], 0, 0, 0);
            acc[1][0] = __builtin_amdgcn_mfma_f32_16x16x32_bf16(af1, B00, acc[1][0], 0, 0, 0);
            acc[1][1] = __builtin_amdgcn_mfma_f32_16x16x32_bf16(af1, B01, acc[1][1], 0, 0, 0);
            acc[1][2] = __builtin_amdgcn_mfma_f32_16x16x32_bf16(af1, B02, acc[1][2], 0, 0, 0);
            acc[1][3] = __builtin_amdgcn_mfma_f32_16x16x32_bf16(af1, B03, acc[1][3], 0, 0, 0);
        }

        // issue loads for step 2p+2 into buf0 (skip on last iteration)
        if (p < 7) {
            A0l0 = *(const float4*)(pa0 + 64);  A0h0 = *(const float4*)(pa0 + 68);
            A0l1 = *(const float4*)(pa1 + 64);  A0h1 = *(const float4*)(pa1 + 68);
            B00 = *(const bf16x8*)(pb + 8192); B01 = *(const bf16x8*)(pb + 8320);
            B02 = *(const bf16x8*)(pb + 8448); B03 = *(const bf16x8*)(pb + 8576);
        }

        // compute step 2p+1 from buf1
        {
            bf16x8 af0 = cvt8(A1l0, A1h0);
            bf16x8 af1 = cvt8(A1l1, A1h1);
            acc[0][0] = __builtin_amdgcn_mfma_f32_16x16x32_bf16(af0, B10, acc[0][0], 0, 0, 0);
            acc[0][1] = __builtin_amdgcn_mfma_f32_16x16x32_bf16(af0, B11, acc[0][1], 0, 0, 0);
            acc[0][2] = __builtin_amdgcn_mfma_f32_16x16x32_bf16(af0, B12, acc[0][2], 0, 0, 0);
            acc[0][3] = __builtin_amdgcn_mfma_f32_16x16x32_bf16(af0, B13, acc[0][3], 0, 0, 0);
            acc[1][0] = __builtin_amdgcn_mfma_f32_16x16x32_bf16(af1, B10, acc[1][0], 0, 0, 0);
            acc[1][1] = __builtin_amdgcn_mfma_f32_16x16x32_bf16(af1, B11, acc[1][1], 0, 0, 0);
            acc[1][2] = __builtin_amdgcn_mfma_f32_16x16x32_bf16(af1, B12, acc[1][2], 0, 0, 0);
            acc[1][3] = __builtin_amdgcn_mfma_f32_16x16x32_bf16(af1, B13, acc[1][3], 0, 0, 0);
        }

        pa0 += 64;
        pa1 += 64;
        pb  += 8192;
    }

    // C/D layout: col = lane&15, row = (lane>>4)*4 + reg. Store bf16.
    const int crow0 = (lane >> 4) * 4;
    const int ccol  = lane & 15;
#pragma unroll
    for (int mf = 0; mf < 2; ++mf)
#pragma unroll
        for (int r = 0; r < 4; ++r) {
            const int grow = block_row + wm * 32 + mf * 16 + crow0 + r;
            if (grow < M) {
                unsigned short* zr = zb + (size_t)grow * OUT_DIM + wn * 64 + ccol;
#pragma unroll
                for (int nf = 0; nf < 4; ++nf)
                    zr[nf * 16] = f2bf(acc[mf][nf][r]);
            }
        }
}

// ---------------------------------------------------------------------------
// Decode: out[e] = sigmoid( sum_k z[a_e,k]*z[b_e,k]*w3[k] ), z in bf16.
// 16 lanes per edge, 4 edges/wave, grid-stride UNROLLED x2 (2x MLP).
// ---------------------------------------------------------------------------
__device__ inline float dotw3(const uint4& ua, const uint4& ub, const f32x2* w3v) {
    const unsigned pa[4] = {ua.x, ua.y, ua.z, ua.w};
    const unsigned pb[4] = {ub.x, ub.y, ub.z, ub.w};
    f32x2 vv = (f32x2){0.f, 0.f};
#pragma unroll
    for (int i = 0; i < 4; ++i) {
        f32x2 A = (f32x2){__uint_as_float(pa[i] << 16),
                          __uint_as_float(pa[i] & 0xFFFF0000u)};
        f32x2 B = (f32x2){__uint_as_float(pb[i] << 16),
                          __uint_as_float(pb[i] & 0xFFFF0000u)};
        vv += (A * B) * w3v[i];  // v_pk_mul_f32 + v_pk_fma_f32
    }
    return vv.x + vv.y;
}

__global__ __launch_bounds__(256) void decode_kernel(const unsigned short* __restrict__ zb,
                                                     const int* __restrict__ e1,
                                                     const int* __restrict__ e2,
                                                     const float* __restrict__ w3,
                                                     float* __restrict__ out,
                                                     int E1, int E2) {
    const int tid  = threadIdx.x;
    const int lane = tid & 63;
    const int sub  = lane & 15;   // lane within 16-group
    const int sg   = lane >> 4;   // edge slot within wave (0..3)
    const int Etot = E1 + E2;
    const int nq   = (Etot + 3) >> 2;

    f32x2 w3v[4];
    {
        const float4 wlo = *(const float4*)(w3 + sub * 8);
        const float4 whi = *(const float4*)(w3 + sub * 8 + 4);
        w3v[0] = (f32x2){wlo.x, wlo.y};
        w3v[1] = (f32x2){wlo.z, wlo.w};
        w3v[2] = (f32x2){whi.x, whi.y};
        w3v[3] = (f32x2){whi.z, whi.w};
    }

    const int wave = blockIdx.x * 4 + (tid >> 6);
    const int S    = gridDim.x * 4;  // stride in quads

    for (int q = wave; q < nq; q += 2 * S) {
        const int q2    = q + S;
        const bool has2 = (q2 < nq);

        const int e_a = q * 4 + sg;
        const int e_b = has2 ? (q2 * 4 + sg) : e_a;
        const int ca  = min(e_a, Etot - 1);
        const int cb  = min(e_b, Etot - 1);

        // both index loads up front
        const int2 ia = (ca < E1) ? ((const int2*)e1)[ca] : ((const int2*)e2)[ca - E1];
        const int2 ib = (cb < E1) ? ((const int2*)e1)[cb] : ((const int2*)e2)[cb - E1];

        // all 4 row gathers issued before any math
        const uint4 a1 = *(const uint4*)(zb + (size_t)ia.x * OUT_DIM + sub * 8);
        const uint4 b1 = *(const uint4*)(zb + (size_t)ia.y * OUT_DIM + sub * 8);
        const uint4 a2 = *(const uint4*)(zb + (size_t)ib.x * OUT_DIM + sub * 8);
        const uint4 b2 = *(const uint4*)(zb + (size_t)ib.y * OUT_DIM + sub * 8);

        float v1 = dotw3(a1, b1, w3v);
        float v2 = dotw3(a2, b2, w3v);

        v1 += __shfl_xor(v1, 8);  v2 += __shfl_xor(v2, 8);
        v1 += __shfl_xor(v1, 4);  v2 += __shfl_xor(v2, 4);
        v1 += __shfl_xor(v1, 2);  v2 += __shfl_xor(v2, 2);
        v1 += __shfl_xor(v1, 1);  v2 += __shfl_xor(v2, 1);

        if (sub == 0) {
            if (e_a < Etot) out[e_a] = 1.f / (1.f + __expf(-v1));
            if (has2 && e_b < Etot) out[e_b] = 1.f / (1.f + __expf(-v2));
        }
    }
}

extern "C" void kernel_launch(void* const* d_in, const int* in_sizes, int n_in,
                              void* d_out, int out_size, void* d_ws, size_t ws_size,
                              hipStream_t stream) {
    const float* x  = (const float*)d_in[0];
    const int*   e1 = (const int*)d_in[1];
    const int*   e2 = (const int*)d_in[2];
    const float* w  = (const float*)d_in[3];
    const float* w3 = (const float*)d_in[4];

    float* out = (float*)d_out;

    const int M  = in_sizes[0] / IN_DIM;  // 100000
    const int E1 = in_sizes[1] / 2;       // 300000
    const int E2 = in_sizes[2] / 2;       // 300000

    // workspace: z_bf [M,128] bf16 (25.6 MB), then wt2 [512x128] bf16 (128 KB)
    unsigned short* zbuf = (unsigned short*)d_ws;
    unsigned short* wt2  = zbuf + (size_t)M * OUT_DIM;

    wt2_kernel<<<(IN_DIM * OUT_DIM) / 256, 256, 0, stream>>>(w, wt2);
    gemm_mfma<<<(M + BM - 1) / BM, 256, 0, stream>>>(x, wt2, zbuf, M);
    decode_kernel<<<2048, 256, 0, stream>>>(zbuf, e1, e2, w3, out, E1, E2);
}

// Round 10
// 87.601 us; speedup vs baseline: 1.3374x; 1.3192x over previous
//
#include <hip/hip_runtime.h>
#include <math.h>

#define IN_DIM 512
#define OUT_DIM 128
#define BM 64
#define BK 64
#define NKT (IN_DIM / BK)  // 8

typedef __attribute__((ext_vector_type(8))) __bf16 bf16x8;
typedef __attribute__((ext_vector_type(2))) __bf16 bf16x2;
typedef __attribute__((ext_vector_type(4))) float f32x4;
typedef __attribute__((ext_vector_type(2))) float f32x2;

// Manual RNE fp32->bf16 (bit ops) — r5-proven codegen for epilogue/prep.
__device__ inline unsigned short f2bf(float f) {
    unsigned u = __float_as_uint(f);
    u += 0x7FFFu + ((u >> 16) & 1u);  // round-to-nearest-even
    return (unsigned short)(u >> 16);
}

// In-register fp32x8 -> bf16x8 via native paired casts (v_cvt_pk_bf16_f32),
// consumed immediately by MFMA (short live ranges).
__device__ inline bf16x8 cvt8(const f32x4& lo, const f32x4& hi) {
    bf16x2 p0 = {(__bf16)lo.x, (__bf16)lo.y};
    bf16x2 p1 = {(__bf16)lo.z, (__bf16)lo.w};
    bf16x2 p2 = {(__bf16)hi.x, (__bf16)hi.y};
    bf16x2 p3 = {(__bf16)hi.z, (__bf16)hi.w};
    uint4 u = {__builtin_bit_cast(unsigned, p0), __builtin_bit_cast(unsigned, p1),
               __builtin_bit_cast(unsigned, p2), __builtin_bit_cast(unsigned, p3)};
    return __builtin_bit_cast(bf16x8, u);
}

// async global->LDS, 16B per lane (dest = wave-uniform base + lane*16)
__device__ inline void gload_lds16(const void* g, void* l) {
    __builtin_amdgcn_global_load_lds(
        (const __attribute__((address_space(1))) void*)g,
        (__attribute__((address_space(3))) void*)l, 16, 0, 0);
}

// w [512][128] f32 -> wt2 k-interleaved bf16: wt2[(k>>3)*128 + n][k&7]
__global__ void wt2_kernel(const float* __restrict__ w, unsigned short* __restrict__ wt2) {
    int idx = blockIdx.x * 256 + threadIdx.x;  // 65536 total
    int k = idx >> 7;
    int n = idx & 127;
    wt2[(((k >> 3) * 128) + n) * 8 + (k & 7)] = f2bf(w[idx]);
}

// ---------------------------------------------------------------------------
// z_bf[M,128](bf16) = x[M,512] @ w[512,128] via bf16 MFMA, fp32 accumulate.
// m97-style 2-phase pipeline: A staged as FP32 via global_load_lds (async
// DMA, width 16) into double-buffered LDS (2 x 16 KB); DMA for tile t+1 is
// issued before computing tile t; __syncthreads() at iteration end drains it.
// Both-sides XOR swizzle (rule 21): linear LDS dest + inverse-swizzled
// SOURCE address + swizzled ds_read (cb ^= (row&7)<<5) -> <=2-way conflicts.
// fp32->bf16 conversion on the consume side (VALU is idle). B fragments
// direct from L2-resident wt2. 4 waves (2x2), wave = 32x64 out.
// ---------------------------------------------------------------------------
__global__ __launch_bounds__(256, 4) void gemm_mfma(const float* __restrict__ x,
                                                    const unsigned short* __restrict__ wt2,
                                                    unsigned short* __restrict__ zb,
                                                    int M) {
    __shared__ float sA[2][BM * BK];  // 2 x 16 KB fp32, col-swizzled
    char* const pAb = (char*)sA;

    const int tid  = threadIdx.x;
    const int lane = tid & 63;
    const int wid  = tid >> 6;
    const int wm   = wid >> 1;  // 0..1
    const int wn   = wid & 1;   // 0..1
    const int block_row = blockIdx.x * BM;

    const int fr  = lane & 15;  // fragment row (A) / col (B)
    const int fk4 = lane >> 4;  // k-octet group 0..3

    f32x4 acc[2][4];
#pragma unroll
    for (int i = 0; i < 2; ++i)
#pragma unroll
        for (int j = 0; j < 4; ++j) acc[i][j] = (f32x4){0.f, 0.f, 0.f, 0.f};

    // ---- staging map: chunk c = wid*4+i covers LDS [c*1024, c*1024+1024)
    // = rows 4c..4c+3 (256 B/row). Lane handles row 4c+(lane>>4),
    // bytes (lane&15)*16. Source col-byte is inverse-swizzled.
    const int s_row = lane >> 4;         // 0..3 within chunk
    const int s_cb  = (lane & 15) * 16;  // 0..240

    // ---- fragment-read map (logical row, swizzled column)
    const int rowa0 = wm * 32 + fr;       // mf=0 row (row&7 == fr&7)
    const int rowa1 = rowa0 + 16;         // mf=1 row (same &7)
    const int swz7  = (fr & 7) << 5;

    // B per-lane base in wt2 (element units)
    const unsigned short* pb = wt2 + fk4 * 1024 + (wn * 64 + fr) * 8;

    // prologue: stage tile 0 into buf0
#pragma unroll
    for (int i = 0; i < 4; ++i) {
        const int rr = (wid * 4 + i) * 4 + s_row;
        int grow = block_row + rr;
        grow = (grow < M) ? grow : (M - 1);
        const char* src = (const char*)x + (size_t)grow * 2048 + (s_cb ^ ((rr & 7) << 5));
        gload_lds16(src, pAb + (wid * 4 + i) * 1024);
    }
    __syncthreads();

#pragma unroll
    for (int kt = 0; kt < NKT; ++kt) {
        const int buf = kt & 1;
        // issue async DMA for tile kt+1 into the other buffer (overlaps MFMA)
        if (kt + 1 < NKT) {
#pragma unroll
            for (int i = 0; i < 4; ++i) {
                const int rr = (wid * 4 + i) * 4 + s_row;
                int grow = block_row + rr;
                grow = (grow < M) ? grow : (M - 1);
                const char* src = (const char*)x + (size_t)grow * 2048 +
                                  (kt + 1) * 256 + (s_cb ^ ((rr & 7) << 5));
                gload_lds16(src, pAb + (buf ^ 1) * 16384 + (wid * 4 + i) * 1024);
            }
        }

        // compute tile kt from buf
        const char* pT = pAb + buf * 16384;
#pragma unroll
        for (int ks = 0; ks < 2; ++ks) {
            const int cb0 = ks * 128 + fk4 * 32;
            f32x4 lo0 = *(const f32x4*)(pT + rowa0 * 256 + (cb0 ^ swz7));
            f32x4 hi0 = *(const f32x4*)(pT + rowa0 * 256 + (cb0 ^ swz7) + 16);
            f32x4 lo1 = *(const f32x4*)(pT + rowa1 * 256 + (cb0 ^ swz7));
            f32x4 hi1 = *(const f32x4*)(pT + rowa1 * 256 + (cb0 ^ swz7) + 16);
            bf16x8 af0 = cvt8(lo0, hi0);
            bf16x8 af1 = cvt8(lo1, hi1);
            bf16x8 bv0 = *(const bf16x8*)(pb + kt * 8192 + ks * 4096 + 0);
            bf16x8 bv1 = *(const bf16x8*)(pb + kt * 8192 + ks * 4096 + 128);
            bf16x8 bv2 = *(const bf16x8*)(pb + kt * 8192 + ks * 4096 + 256);
            bf16x8 bv3 = *(const bf16x8*)(pb + kt * 8192 + ks * 4096 + 384);
            acc[0][0] = __builtin_amdgcn_mfma_f32_16x16x32_bf16(af0, bv0, acc[0][0], 0, 0, 0);
            acc[0][1] = __builtin_amdgcn_mfma_f32_16x16x32_bf16(af0, bv1, acc[0][1], 0, 0, 0);
            acc[0][2] = __builtin_amdgcn_mfma_f32_16x16x32_bf16(af0, bv2, acc[0][2], 0, 0, 0);
            acc[0][3] = __builtin_amdgcn_mfma_f32_16x16x32_bf16(af0, bv3, acc[0][3], 0, 0, 0);
            acc[1][0] = __builtin_amdgcn_mfma_f32_16x16x32_bf16(af1, bv0, acc[1][0], 0, 0, 0);
            acc[1][1] = __builtin_amdgcn_mfma_f32_16x16x32_bf16(af1, bv1, acc[1][1], 0, 0, 0);
            acc[1][2] = __builtin_amdgcn_mfma_f32_16x16x32_bf16(af1, bv2, acc[1][2], 0, 0, 0);
            acc[1][3] = __builtin_amdgcn_mfma_f32_16x16x32_bf16(af1, bv3, acc[1][3], 0, 0, 0);
        }
        __syncthreads();  // drains DMA(kt+1) + gates buffer reuse
    }

    // C/D layout: col = lane&15, row = (lane>>4)*4 + reg. Store bf16.
    const int crow0 = (lane >> 4) * 4;
    const int ccol  = lane & 15;
#pragma unroll
    for (int mf = 0; mf < 2; ++mf)
#pragma unroll
        for (int r = 0; r < 4; ++r) {
            const int grow = block_row + wm * 32 + mf * 16 + crow0 + r;
            if (grow < M) {
                unsigned short* zr = zb + (size_t)grow * OUT_DIM + wn * 64 + ccol;
#pragma unroll
                for (int nf = 0; nf < 4; ++nf)
                    zr[nf * 16] = f2bf(acc[mf][nf][r]);
            }
        }
}

// ---------------------------------------------------------------------------
// Decode: out[e] = sigmoid( sum_k z[a_e,k]*z[b_e,k]*w3[k] ), z in bf16.
// 16 lanes per edge, 4 edges/wave, grid-stride UNROLLED x2 (2x MLP).
// ---------------------------------------------------------------------------
__device__ inline float dotw3(const uint4& ua, const uint4& ub, const f32x2* w3v) {
    const unsigned pa[4] = {ua.x, ua.y, ua.z, ua.w};
    const unsigned pb[4] = {ub.x, ub.y, ub.z, ub.w};
    f32x2 vv = (f32x2){0.f, 0.f};
#pragma unroll
    for (int i = 0; i < 4; ++i) {
        f32x2 A = (f32x2){__uint_as_float(pa[i] << 16),
                          __uint_as_float(pa[i] & 0xFFFF0000u)};
        f32x2 B = (f32x2){__uint_as_float(pb[i] << 16),
                          __uint_as_float(pb[i] & 0xFFFF0000u)};
        vv += (A * B) * w3v[i];  // v_pk_mul_f32 + v_pk_fma_f32
    }
    return vv.x + vv.y;
}

__global__ __launch_bounds__(256) void decode_kernel(const unsigned short* __restrict__ zb,
                                                     const int* __restrict__ e1,
                                                     const int* __restrict__ e2,
                                                     const float* __restrict__ w3,
                                                     float* __restrict__ out,
                                                     int E1, int E2) {
    const int tid  = threadIdx.x;
    const int lane = tid & 63;
    const int sub  = lane & 15;   // lane within 16-group
    const int sg   = lane >> 4;   // edge slot within wave (0..3)
    const int Etot = E1 + E2;
    const int nq   = (Etot + 3) >> 2;

    f32x2 w3v[4];
    {
        const float4 wlo = *(const float4*)(w3 + sub * 8);
        const float4 whi = *(const float4*)(w3 + sub * 8 + 4);
        w3v[0] = (f32x2){wlo.x, wlo.y};
        w3v[1] = (f32x2){wlo.z, wlo.w};
        w3v[2] = (f32x2){whi.x, whi.y};
        w3v[3] = (f32x2){whi.z, whi.w};
    }

    const int wave = blockIdx.x * 4 + (tid >> 6);
    const int S    = gridDim.x * 4;  // stride in quads

    for (int q = wave; q < nq; q += 2 * S) {
        const int q2    = q + S;
        const bool has2 = (q2 < nq);

        const int e_a = q * 4 + sg;
        const int e_b = has2 ? (q2 * 4 + sg) : e_a;
        const int ca  = min(e_a, Etot - 1);
        const int cb  = min(e_b, Etot - 1);

        // both index loads up front
        const int2 ia = (ca < E1) ? ((const int2*)e1)[ca] : ((const int2*)e2)[ca - E1];
        const int2 ib = (cb < E1) ? ((const int2*)e1)[cb] : ((const int2*)e2)[cb - E1];

        // all 4 row gathers issued before any math
        const uint4 a1 = *(const uint4*)(zb + (size_t)ia.x * OUT_DIM + sub * 8);
        const uint4 b1 = *(const uint4*)(zb + (size_t)ia.y * OUT_DIM + sub * 8);
        const uint4 a2 = *(const uint4*)(zb + (size_t)ib.x * OUT_DIM + sub * 8);
        const uint4 b2 = *(const uint4*)(zb + (size_t)ib.y * OUT_DIM + sub * 8);

        float v1 = dotw3(a1, b1, w3v);
        float v2 = dotw3(a2, b2, w3v);

        v1 += __shfl_xor(v1, 8);  v2 += __shfl_xor(v2, 8);
        v1 += __shfl_xor(v1, 4);  v2 += __shfl_xor(v2, 4);
        v1 += __shfl_xor(v1, 2);  v2 += __shfl_xor(v2, 2);
        v1 += __shfl_xor(v1, 1);  v2 += __shfl_xor(v2, 1);

        if (sub == 0) {
            if (e_a < Etot) out[e_a] = 1.f / (1.f + __expf(-v1));
            if (has2 && e_b < Etot) out[e_b] = 1.f / (1.f + __expf(-v2));
        }
    }
}

extern "C" void kernel_launch(void* const* d_in, const int* in_sizes, int n_in,
                              void* d_out, int out_size, void* d_ws, size_t ws_size,
                              hipStream_t stream) {
    const float* x  = (const float*)d_in[0];
    const int*   e1 = (const int*)d_in[1];
    const int*   e2 = (const int*)d_in[2];
    const float* w  = (const float*)d_in[3];
    const float* w3 = (const float*)d_in[4];

    float* out = (float*)d_out;

    const int M  = in_sizes[0] / IN_DIM;  // 100000
    const int E1 = in_sizes[1] / 2;       // 300000
    const int E2 = in_sizes[2] / 2;       // 300000

    // workspace: z_bf [M,128] bf16 (25.6 MB), then wt2 [512x128] bf16 (128 KB)
    unsigned short* zbuf = (unsigned short*)d_ws;
    unsigned short* wt2  = zbuf + (size_t)M * OUT_DIM;

    wt2_kernel<<<(IN_DIM * OUT_DIM) / 256, 256, 0, stream>>>(w, wt2);
    gemm_mfma<<<(M + BM - 1) / BM, 256, 0, stream>>>(x, wt2, zbuf, M);
    decode_kernel<<<2048, 256, 0, stream>>>(zbuf, e1, e2, w3, out, E1, E2);
}